// Round 13
// baseline (1076.418 us; speedup 1.0000x reference)
//
#include <hip/hip_runtime.h>
#include <hip/hip_bf16.h>
#include <cfloat>
#include <cstdint>

// ---------------------------------------------------------------------------
// RPN pipeline (B=1): conv3d(256->512,3x3x3,SAME)+ReLU -> heads -> proposals
// Round-25: conv occupancy push WITHOUT touching the v-dim machinery.
// Tile 128x128 -> 64o x 128v, grid (128,8)=1024 blocks, single-buffer 24KB
// LDS, __launch_bounds__(256,4) -> 4 blocks/CU = 4 waves/SIMD (was 2).
// Staging writes, B-fragment reads, and wave-per-v-group sharing are
// byte-identical to the converged r16 kernel (r13's retile regression came
// from changing those). A-reg dbuf kept. 2 LDS-only barriers per stage.
// Per-output MFMA sequence unchanged -> conv1 bit-identical.
// ---------------------------------------------------------------------------

#define T_DIM 16
#define H_DIM 32
#define W_DIM 32
#define NVOX  (T_DIM*H_DIM*W_DIM)   // 16384
#define HW    (H_DIM*W_DIM)         // 1024
#define CIN   256
#define COUT  512
#define PRE_NMS 1000
#define POST_NMS 128
#define NMS_TH 0.7f

typedef __attribute__((ext_vector_type(8))) short v8s;
typedef __attribute__((ext_vector_type(4))) float v4f;
typedef __attribute__((ext_vector_type(4))) int v4i;

#define MFMA_B16(A,B,C) __builtin_amdgcn_mfma_f32_16x16x32_bf16(A,B,C,0,0,0)

__device__ __forceinline__ short f2bf(float x) {
    unsigned u = __float_as_uint(x);
    u += 0x7FFFu + ((u >> 16) & 1u);
    return (short)(u >> 16);
}
__device__ __forceinline__ float bf2f(short s) {
    return __uint_as_float(((unsigned)(unsigned short)s) << 16);
}

__constant__ float c_ws[3] = {23.f, 16.f, 11.f};
__constant__ float c_hs[3] = {12.f, 16.f, 22.f};
__constant__ float c_sc[3] = {4.f, 8.f, 16.f};
__constant__ float c_depth[3] = {16.f, 8.f, 4.f};

// ---------------------------------------------------------------------------
// Weight split v2, FRAGMENT-MAJOR out: Af[((tap*32+ko)*512+o)*8+c7], c=ko*8+c7.
__global__ __launch_bounds__(256) void k_split_w(const float* __restrict__ W,
                                                 short* __restrict__ A0,
                                                 short* __restrict__ A1,
                                                 short* __restrict__ A2) {
    __shared__ float Wl[4][3456];         // 55.3 KB
    const int b = blockIdx.x;             // 256 blocks
    const int t = threadIdx.x;
    const int og = b >> 1;                // o = og*4 + ol
    const int ch = b & 1;                 // c = ch*128 + cl
#pragma unroll
    for (int k = 0; k < 54; ++k) {
        int fi = t + k * 256;             // 0..13823
        int ol = fi / 3456;
        int idx = fi - ol * 3456;         // = cl*27 + tap
        Wl[ol][idx] = W[(size_t)(og * 4 + ol) * 6912 + ch * 3456 + idx];
    }
    __syncthreads();
    for (int p = t; p < 432; p += 256) {
        int tap = p >> 4, kol = p & 15;
        int ko = ch * 16 + kol;
        v8s vh[4], vm[4], vl[4];
#pragma unroll
        for (int ol = 0; ol < 4; ++ol)
#pragma unroll
            for (int c7 = 0; c7 < 8; ++c7) {
                float x = Wl[ol][(kol * 8 + c7) * 27 + tap];
                short hh = f2bf(x); float r = x - bf2f(hh);
                short mm = f2bf(r); float r2 = r - bf2f(mm);
                short ll = f2bf(r2);
                vh[ol][c7] = hh; vm[ol][c7] = mm; vl[ol][c7] = ll;
            }
        size_t base = ((size_t)(tap * 32 + ko) * 512 + og * 4) * 8;
#pragma unroll
        for (int q = 0; q < 4; ++q) {
            *(v8s*)(A0 + base + q * 8) = vh[q];
            *(v8s*)(A1 + base + q * 8) = vm[q];
            *(v8s*)(A2 + base + q * 8) = vl[q];
        }
    }
}

// ---------------------------------------------------------------------------
// bit-trick split of 2 floats -> 3 packed bf16-pair ints (low = X0, high = X1)
#define SPLIT2(X0, X1, OH, OM, OL) {                                          \
    unsigned u0_ = __float_as_uint(X0), u1_ = __float_as_uint(X1);            \
    OH = (int)__builtin_amdgcn_perm(u1_, u0_, 0x07060302u);                   \
    float h0_ = __uint_as_float(u0_ & 0xFFFF0000u);                           \
    float h1_ = __uint_as_float(u1_ & 0xFFFF0000u);                           \
    float r0_ = (X0) - h0_, r1_ = (X1) - h1_;                                 \
    unsigned v0_ = __float_as_uint(r0_), v1_ = __float_as_uint(r1_);          \
    OM = (int)__builtin_amdgcn_perm(v1_, v0_, 0x07060302u);                   \
    float m0_ = __uint_as_float(v0_ & 0xFFFF0000u);                           \
    float m1_ = __uint_as_float(v1_ & 0xFFFF0000u);                           \
    float s0_ = r0_ - m0_, s1_ = r1_ - m1_;                                   \
    OL = (int)__builtin_amdgcn_perm(__float_as_uint(s1_),                     \
                                    __float_as_uint(s0_), 0x07060302u);       \
}

// k_prep: fused  (a) Wcomb build [512 blocks]  (b) input pre-split [2048 blocks].
__global__ void k_prep(const float* __restrict__ Wcls, const float* __restrict__ Wbb,
                       float* __restrict__ Wc, const float* __restrict__ I,
                       v4i* __restrict__ Ih, v4i* __restrict__ Im,
                       v4i* __restrict__ Il) {
    int blk = blockIdx.x;
    if (blk < 512) {
        int i = blk * 256 + threadIdx.x;  // over 512*256
        int o = i & 255;
        int c = i >> 8;
        float v = 0.f;
        if (o < 54) v = Wcls[o * 512 + c];
        else if (o < 216) v = Wbb[(o - 54) * 512 + c];
        Wc[i] = v;
    } else {
        int t = (blk - 512) * 256 + threadIdx.x;   // over 32*16384 = 524288
        int vox = t & 16383;
        int ck8 = t >> 14;
        const float* ip = I + ((size_t)ck8 << 3) * NVOX + vox;
        int h[4], m[4], l[4];
#pragma unroll
        for (int j = 0; j < 4; ++j) {
            float x0 = ip[(size_t)(2 * j) * NVOX];
            float x1 = ip[(size_t)(2 * j + 1) * NVOX];
            SPLIT2(x0, x1, h[j], m[j], l[j]);
        }
        Ih[t] = (v4i){h[0], h[1], h[2], h[3]};
        Im[t] = (v4i){m[0], m[1], m[2], m[3]};
        Il[t] = (v4i){l[0], l[1], l[2], l[3]};
    }
}

#define CV_SHIFT(TAP) {                                                       \
    int kt_ = (TAP) / 9 - 1, kh_ = ((TAP) / 3) % 3 - 1, kw_ = (TAP) % 3 - 1;  \
    int tt_ = bt + kt_, hh_ = bh + kh_, ww_ = bw + kw_;                       \
    bVal = ((unsigned)tt_ < 16u) && ((unsigned)hh_ < 32u) && ((unsigned)ww_ < 32u); \
    bOff = bVal ? ((tt_ << 10) + (hh_ << 5) + ww_) : 0;                       \
}

// prefetch pre-split B raw regs (in flight during compute).
#define CV_LOAD_BP(CK8B) {                                                    \
    const size_t bidx_ = (((size_t)((CK8B) + skh * 2)) << 14) + bOff;         \
    nh0 = Ih[bidx_]; nh1 = Ih[bidx_ + NVOX];                                  \
    nm0 = Im[bidx_]; nm1 = Im[bidx_ + NVOX];                                  \
    nl0 = Il[bidx_]; nl1 = Il[bidx_ + NVOX];                                  \
}

// A-set for a 32-o wave: 2 row-blocks per plane (offsets +0, +128 shorts).
#define LOAD_ASET_M(S, H0,H1, M0,M1, L0,L1) {                                 \
    const size_t aB_ = (((size_t)((S) >> 3) * 32 + (((S) & 7) << 2)) << 12) + aLane; \
    H0 = *(const v8s*)(A0 + aB_); H1 = *(const v8s*)(A0 + aB_ + 128);         \
    M0 = *(const v8s*)(A1 + aB_); M1 = *(const v8s*)(A1 + aB_ + 128);         \
    L0 = *(const v8s*)(A2 + aB_); L1 = *(const v8s*)(A2 + aB_ + 128);         \
}

#define COMPUTE_M(H0,H1, M0,M1, L0,L1) {                                      \
    _Pragma("unroll")                                                         \
    for (int j = 0; j < 4; ++j) {                                             \
        v8s bb = *(const v8s*)(&Bsh[0][uB + j * 16]);                         \
        v8s bm = *(const v8s*)(&Bsh[1][uB + j * 16]);                         \
        v8s bl = *(const v8s*)(&Bsh[2][uB + j * 16]);                         \
        v4f a;                                                                \
        a = acc[0][j];                                                        \
        a = MFMA_B16(H0, bb, a); a = MFMA_B16(H0, bm, a);                     \
        a = MFMA_B16(M0, bb, a); a = MFMA_B16(H0, bl, a);                     \
        a = MFMA_B16(M0, bm, a); a = MFMA_B16(L0, bb, a);                     \
        acc[0][j] = a;                                                        \
        a = acc[1][j];                                                        \
        a = MFMA_B16(H1, bb, a); a = MFMA_B16(H1, bm, a);                     \
        a = MFMA_B16(M1, bb, a); a = MFMA_B16(H1, bl, a);                     \
        a = MFMA_B16(M1, bm, a); a = MFMA_B16(L1, bb, a);                     \
        acc[1][j] = a;                                                        \
    }                                                                         \
}

// Variadic forwarders: expand ASET(x) before parameter matching.
#define LOAD_ASET(S, ...) LOAD_ASET_M(S, __VA_ARGS__)
#define COMPUTE(...) COMPUTE_M(__VA_ARGS__)

#define ASET(P) P##h0,P##h1,P##m0,P##m1,P##l0,P##l1

// LDS-only barrier (global prefetches stay in flight).
#define BAR_LDS() { asm volatile("s_waitcnt lgkmcnt(0)" ::: "memory");        \
                    __builtin_amdgcn_s_barrier(); }

// One stage: drain-reads barrier, write B(s) to LDS, barrier, prefetch
// raw B(s+1) + A(s+1)->ALT, compute with CUR. Same MFMA order per output.
#define ITER1(SS, CUR, ALT) {                                                 \
    BAR_LDS();                                                                \
    {                                                                         \
        v4i z_ = (v4i){0, 0, 0, 0};                                           \
        Bsh[0][uW0] = bValCur ? nh0 : z_;                                     \
        Bsh[0][uW1] = bValCur ? nh1 : z_;                                     \
        Bsh[1][uW0] = bValCur ? nm0 : z_;                                     \
        Bsh[1][uW1] = bValCur ? nm1 : z_;                                     \
        Bsh[2][uW0] = bValCur ? nl0 : z_;                                     \
        Bsh[2][uW1] = bValCur ? nl1 : z_;                                     \
    }                                                                         \
    BAR_LDS();                                                                \
    {                                                                         \
        int s1_ = (SS) + 1;                                                   \
        if (s1_ < 216) {                                                      \
            if ((s1_ & 7) == 0) CV_SHIFT(s1_ >> 3);                           \
            CV_LOAD_BP((s1_ & 7) << 2);                                       \
            bValCur = bVal;                                                   \
            LOAD_ASET(s1_, ASET(ALT));                                        \
        }                                                                     \
    }                                                                         \
    COMPUTE(ASET(CUR));                                                       \
}

// MFMA conv3d: 64o x 128v tile, 4 waves in 2x2 (each 32o x 64v), BK=32.
// Grid (128,8)=1024 blocks; 24KB single-buffer LDS -> 4 blocks/CU.
__global__ __launch_bounds__(256, 4) void k_conv3d_mfma(
        const v4i* __restrict__ Ih, const v4i* __restrict__ Im,
        const v4i* __restrict__ Il, const short* __restrict__ A0,
        const short* __restrict__ A1, const short* __restrict__ A2,
        const float* __restrict__ bias, float* __restrict__ O) {
    __shared__ v4i Bsh[3][512];   // 24 KB (single buffer)
    const int tid = threadIdx.x;
    const int o0 = blockIdx.y * 64;
    const int v0 = blockIdx.x * 128;
    const int lane = tid & 63;
    const int wv = tid >> 6;
    const int quad = lane >> 4, m16 = lane & 15;
    const int wo = (wv >> 1) * 32;        // wave o-origin within tile
    const int wvx = (wv & 1) * 64;        // wave v-origin within tile

    // B staging: row sa_o = tid>>1 (0..127), k-half skh = tid&1  (unchanged)
    const int sa_o = tid >> 1, skh = tid & 1;
    const int uW0 = (skh * 2) * 128 + sa_o;
    const int uW1 = (skh * 2 + 1) * 128 + sa_o;

    const int vbase = v0 + sa_o;
    const int bt = vbase >> 10, bh = (vbase >> 5) & 31, bw = vbase & 31;

    // B fragment read base: [quad*128 + wvx + j*16 + m16]  (unchanged)
    const int uB = quad * 128 + wvx + m16;

    // A fragment global base offset (shorts): lane part
    const size_t aLane = ((size_t)(o0 + wo + m16) << 3) + ((size_t)quad << 12);

    v4f acc[2][4];
#pragma unroll
    for (int i = 0; i < 2; i++)
#pragma unroll
        for (int j = 0; j < 4; j++) acc[i][j] = (v4f){0.f, 0.f, 0.f, 0.f};

    int bOff, bVal, bValCur;
    v4i nh0, nh1, nm0, nm1, nl0, nl1;
    v8s Ph0, Ph1, Pm0, Pm1, Pl0, Pl1;
    v8s Qh0, Qh1, Qm0, Qm1, Ql0, Ql1;

    // prologue: raw B(0) in regs, A(0) in P
    CV_SHIFT(0);
    bValCur = bVal;
    CV_LOAD_BP(0);
    LOAD_ASET(0, ASET(P));

    for (int s = 0; s < 216; s += 2) {
        ITER1(s, P, Q);                   // write B(s), compute A(s)=P
        ITER1(s + 1, Q, P);               // write B(s+1), compute A(s+1)=Q
    }

    // epilogue: per 16x16 tile, col = m16 (v), row = quad*4 + reg (o)
#pragma unroll
    for (int i = 0; i < 2; ++i) {
#pragma unroll
        for (int r = 0; r < 4; ++r) {
            int o = o0 + wo + i * 16 + quad * 4 + r;
            float bo = bias[o];
            float* dst = O + (size_t)o * NVOX + v0 + wvx + m16;
#pragma unroll
            for (int j = 0; j < 4; ++j)
                dst[j * 16] = fmaxf(acc[i][j][r] + bo, 0.f);
        }
    }
}

// ---------------------------------------------------------------------------
// logits3 GEMM: L[o][v] = sum_c Wc[c][o] * conv1[c][v], M=256 (padded), K=512, N=16384
__global__ __launch_bounds__(256) void k_gemm_logits3(const float* __restrict__ conv1,
                                                      const float* __restrict__ Wc,
                                                      float* __restrict__ L) {
    __shared__ float As[16][64];
    __shared__ float Bs[16][64];
    const int tid = threadIdx.x;
    const int o0 = blockIdx.y * 64;
    const int v0 = blockIdx.x * 64;
    const int ty = tid >> 4, tx = tid & 15;
    const int c_l = tid >> 4, e4 = (tid & 15) << 2;

    float acc[4][4];
#pragma unroll
    for (int i = 0; i < 4; i++)
#pragma unroll
        for (int j = 0; j < 4; j++) acc[i][j] = 0.f;

    for (int ck = 0; ck < 512; ck += 16) {
        __syncthreads();
        *(float4*)(&As[c_l][e4]) = *(const float4*)(Wc + ((size_t)(ck + c_l) << 8) + o0 + e4);
        *(float4*)(&Bs[c_l][e4]) = *(const float4*)(conv1 + ((size_t)(ck + c_l) << 14) + v0 + e4);
        __syncthreads();
#pragma unroll
        for (int k = 0; k < 16; ++k) {
            float a[4], b[4];
            *(float4*)(a) = *(const float4*)(&As[k][ty * 4]);
            *(float4*)(b) = *(const float4*)(&Bs[k][tx * 4]);
#pragma unroll
            for (int i = 0; i < 4; i++)
#pragma unroll
                for (int j = 0; j < 4; j++)
                    acc[i][j] = fmaf(a[i], b[j], acc[i][j]);
        }
    }
#pragma unroll
    for (int i = 0; i < 4; i++) {
        float* dst = L + (size_t)(o0 + ty * 4 + i) * NVOX + v0 + tx * 4;
        *(float4*)(dst) = *(const float4*)(&acc[i][0]);
    }
}

// ---------------------------------------------------------------------------
// Fused heads for the 3D branch: sc3 | dl3 | feat2 in one launch.
__global__ void k_heads3(const float* __restrict__ L, const float* __restrict__ b_cls,
                         const float* __restrict__ b_bbox, const float* __restrict__ conv1,
                         float* __restrict__ sc3, float* __restrict__ dl3,
                         float* __restrict__ feat2) {
    int i = blockIdx.x * 256 + threadIdx.x;
    if (i < 27 * HW) {
        int a = i >> 10, hw = i & 1023;
        float b0 = b_cls[a], b1 = b_cls[27 + a];
        const float* L0 = L + (size_t)a * NVOX + hw;
        const float* L1 = L + (size_t)(27 + a) * NVOX + hw;
        float s = 0.f;
        for (int t = 0; t < T_DIM; t++) {
            float x0 = L0[t * HW] + b0, x1 = L1[t * HW] + b1;
            float m = fmaxf(x0, x1);
            float e0 = expf(x0 - m), e1 = expf(x1 - m);
            s += e1 / (e0 + e1);
        }
        sc3[hw * 27 + a] = s * (1.f / 16.f);
    } else if (i < (27 + 162) * HW) {
        int ii = i - 27 * HW;
        int ch = ii >> 10, hw = ii & 1023;
        const float* Lr = L + (size_t)(54 + ch) * NVOX + hw;
        float s = 0.f;
        for (int t = 0; t < T_DIM; t++) s += Lr[t * HW];
        s = s * (1.f / 16.f) + b_bbox[ch];
        int a = ch / 6, d = ch - a * 6;
        dl3[((size_t)hw * 27 + a) * 6 + d] = s;
    } else {
        int ii = i - (27 + 162) * HW;   // 0..524287
        int c = ii >> 10, hw = ii & 1023;
        const float* src = conv1 + (size_t)c * NVOX + hw;
        float s = 0.f;
        for (int t = 0; t < T_DIM; t++) s += src[t * HW];
        feat2[ii] = s * (1.f / 16.f);
    }
}

__global__ void k_gemm2d(const float* __restrict__ feat2, const float* __restrict__ Wcls16,
                         const float* __restrict__ Wbb16, float* __restrict__ L2) {
    int g = blockIdx.x * 256 + threadIdx.x;   // 55296
    int o = g >> 10, hw = g & 1023;
    const float* wrow = (o < 18) ? (Wcls16 + (size_t)o * 512) : (Wbb16 + (size_t)(o - 18) * 512);
    float s = 0.f;
    for (int c = 0; c < 512; c++) s = fmaf(wrow[c], feat2[(size_t)c * HW + hw], s);
    L2[(size_t)o * HW + hw] = s;
}

// Fused heads for the 2D branch: sc2 | dl2 (9*HW + 36*HW = 180 blocks).
__global__ void k_heads2(const float* __restrict__ L2, const float* __restrict__ b_cls16,
                         const float* __restrict__ b_bbox16,
                         float* __restrict__ sc2, float* __restrict__ dl2) {
    int i = blockIdx.x * 256 + threadIdx.x;
    if (i < 9 * HW) {
        int a = i >> 10, hw = i & 1023;
        float x0 = L2[(size_t)a * HW + hw] + b_cls16[a];
        float x1 = L2[(size_t)(9 + a) * HW + hw] + b_cls16[9 + a];
        float m = fmaxf(x0, x1);
        float e0 = expf(x0 - m), e1 = expf(x1 - m);
        sc2[hw * 9 + a] = e1 / (e0 + e1);
    } else if (i < 45 * HW) {
        int ii = i - 9 * HW;
        int ch = ii >> 10, hw = ii & 1023;
        float v = L2[(size_t)(18 + ch) * HW + hw] + b_bbox16[ch];
        int a = ch >> 2, d = ch & 3;
        dl2[((size_t)hw * 9 + a) * 4 + d] = v;
    }
}

// ---------------------------------------------------------------------------
__device__ __forceinline__ unsigned mapf(float f) {
    unsigned u = __float_as_uint(f);
    return (u & 0x80000000u) ? ~u : (u | 0x80000000u);
}

// propA: radix-select + compaction + bitonic sort + decode -> bxg (global).
__global__ __launch_bounds__(1024) void k_propA(const float* __restrict__ im_info,
                                                const float* __restrict__ sc3,
                                                const float* __restrict__ dl3,
                                                const float* __restrict__ sc2,
                                                const float* __restrict__ dl2,
                                                float* __restrict__ bxg) {
    const int branch = blockIdx.x;
    const int tid = threadIdx.x;
    const int A = (branch == 0) ? 27 : 9;
    const int nd = (branch == 0) ? 3 : 2;
    const float* scores = (branch == 0) ? sc3 : sc2;
    const float* deltas = (branch == 0) ? dl3 : dl2;
    const int K = PRE_NMS;
    const int ept = A;
    const int base = tid * ept;

    __shared__ unsigned hist[256];
    __shared__ unsigned long long keys[1024];
    __shared__ unsigned wsum[16];
    __shared__ int sh_b, sh_next;

    // ================= radix-select =========================================
    unsigned prefix = 0;
    int rank = K;
    for (int shift = 24; shift >= 0; shift -= 8) {
        if (tid < 256) hist[tid] = 0;
        __syncthreads();
        const unsigned mask_hi = (shift == 24) ? 0u : (0xFFFFFFFFu << (shift + 8));
        for (int j = 0; j < ept; j++) {
            unsigned m = mapf(scores[base + j]);
            if ((m & mask_hi) == prefix)
                atomicAdd(&hist[(m >> shift) & 255], 1u);
        }
        __syncthreads();
        for (int d = 1; d < 256; d <<= 1) {
            unsigned add = 0;
            if (tid < 256 && tid + d < 256) add = hist[tid + d];
            __syncthreads();
            if (tid < 256) hist[tid] += add;
            __syncthreads();
        }
        if (tid < 256) {
            bool win = (hist[tid] >= (unsigned)rank) &&
                       (tid == 255 || hist[tid + 1] < (unsigned)rank);
            if (win) { sh_b = tid; sh_next = (tid == 255) ? 0 : (int)hist[tid + 1]; }
        }
        __syncthreads();
        prefix |= (unsigned)sh_b << shift;
        rank -= sh_next;
        __syncthreads();
    }
    const unsigned tau = prefix;

    // ================= compaction ===========================================
    int gt_c = 0, eq_c = 0;
    for (int j = 0; j < ept; j++) {
        unsigned m = mapf(scores[base + j]);
        gt_c += (m > tau);
        eq_c += (m == tau);
    }
    unsigned cnt = ((unsigned)gt_c << 16) | (unsigned)eq_c;
    const int lane = tid & 63, wid = tid >> 6;
    unsigned x = cnt;
    for (int d = 1; d < 64; d <<= 1) {
        unsigned y = __shfl_up(x, d);
        if (lane >= d) x += y;
    }
    if (lane == 63) wsum[wid] = x;
    __syncthreads();
    if (wid == 0) {
        unsigned w = (lane < 16) ? wsum[lane] : 0;
        for (int d = 1; d < 16; d <<= 1) {
            unsigned y = __shfl_up(w, d);
            if (lane >= d) w += y;
        }
        if (lane < 16) wsum[lane] = w;
    }
    __syncthreads();
    unsigned excl = x - cnt + (wid ? wsum[wid - 1] : 0);
    const int c1 = (int)(wsum[15] >> 16);
    int gi = (int)(excl >> 16);
    int ei = (int)(excl & 0xFFFFu);
    for (int j = 0; j < ept; j++) {
        int idx = base + j;
        unsigned m = mapf(scores[idx]);
        unsigned long long key = ((unsigned long long)m << 32) |
                                 (unsigned)(0xFFFFFFFFu - (unsigned)idx);
        if (m > tau) {
            keys[gi++] = key;
        } else if (m == tau) {
            if (c1 + ei < K) keys[c1 + ei] = key;
            ei++;
        }
    }
    if (tid < 1024 - K) keys[K + tid] = 0;
    __syncthreads();

    // ================= bitonic sort (desc) ==================================
    for (int k = 2; k <= 1024; k <<= 1) {
        for (int j = k >> 1; j > 0; j >>= 1) {
            int ixj = tid ^ j;
            if (ixj > tid) {
                unsigned long long a = keys[tid], b = keys[ixj];
                bool sw2 = ((tid & k) == 0) ? (a < b) : (a > b);
                if (sw2) { keys[tid] = b; keys[ixj] = a; }
            }
            __syncthreads();
        }
    }

    // ================= decode + clip -> bxg =================================
    const float imh = im_info[0], imw = im_info[1];
    if (tid < K) {
        int n = (int)(0xFFFFFFFFu - (unsigned)(keys[tid] & 0xFFFFFFFFull));
        int cell = n / A, a = n - cell * A;
        int hc = cell >> 5, wc = cell & 31;
        int a2 = (branch == 0) ? (a % 9) : a;
        int ri = a2 / 3, si = a2 % 3;
        float w = c_ws[ri] * c_sc[si], h = c_hs[ri] * c_sc[si];
        float lo[3], hi[3], mx[3];
        lo[0] = 7.5f - (w - 1.f) * 0.5f + 16.f * wc;
        hi[0] = 7.5f + (w - 1.f) * 0.5f + 16.f * wc;
        mx[0] = imw - 1.f;
        lo[1] = 7.5f - (h - 1.f) * 0.5f + 16.f * hc;
        hi[1] = 7.5f + (h - 1.f) * 0.5f + 16.f * hc;
        mx[1] = imh - 1.f;
        if (branch == 0) { lo[2] = 0.f; hi[2] = c_depth[a / 9] - 1.f; mx[2] = (float)(T_DIM - 1); }
        const float* dp = deltas + (size_t)n * (2 * nd);
        float* bp = bxg + ((size_t)branch * PRE_NMS + tid) * 6;
        for (int d = 0; d < nd; d++) {
            float size = hi[d] - lo[d] + 1.f;
            float ctr = lo[d] + 0.5f * (size - 1.f);
            float pctr = dp[d] * size + ctr;
            float psize = expf(dp[nd + d]) * size;
            float pl = pctr - 0.5f * (psize - 1.f);
            float ph = pctr + 0.5f * (psize - 1.f);
            bp[d]      = fminf(fmaxf(pl, 0.f), mx[d]);
            bp[nd + d] = fminf(fmaxf(ph, 0.f), mx[d]);
        }
    }
}

// k_iou: suppression bitmask matrix. Same FP formula/order as the original
// in-loop IoU -> identical comparison bits -> identical keep list.
__global__ __launch_bounds__(256) void k_iou(const float* __restrict__ bxg,
                                             unsigned long long* __restrict__ masks) {
    int g = blockIdx.x * 256 + threadIdx.x;   // 2*1000*16 = 32000
    if (g >= 2 * PRE_NMS * 16) return;
    int branch = g / (PRE_NMS * 16);
    int rem = g - branch * (PRE_NMS * 16);
    int r = rem >> 4, w = rem & 15;
    int nd = (branch == 0) ? 3 : 2;
    const float* B = bxg + (size_t)branch * PRE_NMS * 6;
    float rb[6];
#pragma unroll
    for (int d = 0; d < 6; d++) rb[d] = B[(size_t)r * 6 + d];
    unsigned long long mword = 0;
    int c0 = w * 64;
    for (int j = 0; j < 64; ++j) {
        int c = c0 + j;
        if (c >= PRE_NMS) break;
        const float* cb = B + (size_t)c * 6;
        float colvol = 1.f;
        for (int d = 0; d < nd; d++) colvol *= (cb[nd + d] - cb[d] + 1.f);
        float inter = 1.f, rvol = 1.f;
        for (int d = 0; d < nd; d++) {
            float slo = rb[d], shi = rb[nd + d];
            float l = fmaxf(slo, cb[d]);
            float hh = fminf(shi, cb[nd + d]);
            inter *= fmaxf(hh - l + 1.f, 0.f);
            rvol *= (shi - slo + 1.f);
        }
        float iou = inter / (rvol + colvol - inter);
        if ((iou > NMS_TH) || (c == r)) mword |= (1ull << j);
    }
    masks[((size_t)branch * PRE_NMS + r) * 16 + w] = mword;
}

// k_nms: greedy over bitmask rows (one wave per branch, alive in registers)
// + fused output write (keep list via LDS, same block).
__global__ __launch_bounds__(64) void k_nms(const unsigned long long* __restrict__ masks,
                                            const float* __restrict__ bxg,
                                            float* __restrict__ out) {
    const int branch = blockIdx.x;
    const int lane = threadIdx.x;
    const unsigned long long* M = masks + (size_t)branch * PRE_NMS * 16;
    __shared__ int keep[POST_NMS];
    unsigned long long alive = 0;
    if (lane < 15) alive = ~0ull;
    else if (lane == 15) alive = (1ull << (PRE_NMS - 15 * 64)) - 1;
    for (int i = 0; i < POST_NMS; ++i) {
        int cand = (lane < 16 && alive) ? (lane * 64 + __ffsll(alive) - 1) : 0x7fffffff;
#pragma unroll
        for (int off = 32; off; off >>= 1)
            cand = min(cand, __shfl_xor(cand, off));
        int sel = (cand == 0x7fffffff) ? 0 : cand;
        if (lane == 0) keep[i] = sel;
        if (lane < 16) alive &= ~M[(size_t)sel * 16 + lane];
    }
    __syncthreads();
    const float* B = bxg + (size_t)branch * PRE_NMS * 6;
    for (int e = lane; e < POST_NMS; e += 64) {
        int k = keep[e];
        if (branch == 0) {
            float* o = out + (size_t)e * 7;
            o[0] = 0.f;
            for (int d = 0; d < 6; d++) o[1 + d] = B[(size_t)k * 6 + d];
        } else {
            float* o = out + 128 * 7 + (size_t)e * 5;
            o[0] = 0.f;
            for (int d = 0; d < 4; d++) o[1 + d] = B[(size_t)k * 6 + d];
        }
    }
    if (branch == 0 && lane == 0) {
        out[1536] = 0.f; out[1537] = 0.f; out[1538] = 0.f; out[1539] = 0.f;
    }
}

// ---------------------------------------------------------------------------
extern "C" void kernel_launch(void* const* d_in, const int* in_sizes, int n_in,
                              void* d_out, int out_size, void* d_ws, size_t ws_size,
                              hipStream_t stream) {
    (void)in_sizes; (void)n_in; (void)out_size; (void)ws_size;
    const float* base_feat = (const float*)d_in[0];
    const float* im_info   = (const float*)d_in[1];
    const float* W_conv    = (const float*)d_in[4];
    const float* b_conv    = (const float*)d_in[5];
    const float* W_cls     = (const float*)d_in[6];
    const float* b_cls     = (const float*)d_in[7];
    const float* W_bbox    = (const float*)d_in[8];
    const float* b_bbox    = (const float*)d_in[9];
    const float* W_cls16   = (const float*)d_in[10];
    const float* b_cls16   = (const float*)d_in[11];
    const float* W_bbox16  = (const float*)d_in[12];
    const float* b_bbox16  = (const float*)d_in[13];
    float* out = (float*)d_out;

    // workspace: A0/A1/A2 (bf16 splits, dead after conv) alias L3
    char* ws = (char*)d_ws;
    const size_t AW = (size_t)27 * 512 * 256;
    short* A0 = (short*)ws;
    short* A1 = A0 + AW;
    short* A2 = A1 + AW;
    float* L3 = (float*)ws;
    size_t off = AW * 3 * sizeof(short);
    float* Wcomb  = (float*)(ws + off); off += (size_t)512 * 256 * 4;
    float* conv1  = (float*)(ws + off); off += (size_t)COUT * NVOX * 4;
    float* feat2  = (float*)(ws + off); off += (size_t)512 * HW * 4;
    float* L2     = (float*)(ws + off); off += (size_t)64 * HW * 4;
    float* sc3    = (float*)(ws + off); off += (size_t)27 * HW * 4;
    float* dl3    = (float*)(ws + off); off += (size_t)27 * HW * 6 * 4;
    float* sc2    = (float*)(ws + off); off += (size_t)9 * HW * 4;
    float* dl2    = (float*)(ws + off); off += (size_t)9 * HW * 4 * 4;
    // pre-split input planes (v4i = 8 channels bf16-pair packed), 8.4 MB each
    v4i* Ih = (v4i*)(ws + off); off += (size_t)32 * NVOX * 16;
    v4i* Im_ = (v4i*)(ws + off); off += (size_t)32 * NVOX * 16;
    v4i* Il = (v4i*)(ws + off); off += (size_t)32 * NVOX * 16;
    // proposal pipeline scratch
    float* bxg = (float*)(ws + off); off += (size_t)2 * PRE_NMS * 6 * 4;
    unsigned long long* masks = (unsigned long long*)(ws + off);
    off += (size_t)2 * PRE_NMS * 16 * 8;

    k_split_w<<<256, 256, 0, stream>>>(W_conv, A0, A1, A2);
    k_prep<<<512 + 2048, 256, 0, stream>>>(W_cls, W_bbox, Wcomb, base_feat, Ih, Im_, Il);
    {
        dim3 g(NVOX / 128, COUT / 64);   // (128, 8) = 1024 blocks
        k_conv3d_mfma<<<g, 256, 0, stream>>>(Ih, Im_, Il, A0, A1, A2, b_conv, conv1);
    }
    {
        dim3 g(NVOX / 64, 4);
        k_gemm_logits3<<<g, 256, 0, stream>>>(conv1, Wcomb, L3);
    }
    k_heads3<<<(27 + 162 + 512) * HW / 256, 256, 0, stream>>>(L3, b_cls, b_bbox, conv1,
                                                              sc3, dl3, feat2);
    k_gemm2d<<<(54 * HW) / 256, 256, 0, stream>>>(feat2, W_cls16, W_bbox16, L2);
    k_heads2<<<(45 * HW) / 256, 256, 0, stream>>>(L2, b_cls16, b_bbox16, sc2, dl2);
    k_propA<<<2, 1024, 0, stream>>>(im_info, sc3, dl3, sc2, dl2, bxg);
    k_iou<<<(2 * PRE_NMS * 16 + 255) / 256, 256, 0, stream>>>(bxg, masks);
    k_nms<<<2, 64, 0, stream>>>(masks, bxg, out);
}

// Round 14
// 918.426 us; speedup vs baseline: 1.1720x; 1.1720x over previous
//
#include <hip/hip_runtime.h>
#include <hip/hip_bf16.h>
#include <cfloat>
#include <cstdint>

// ---------------------------------------------------------------------------
// RPN pipeline (B=1): conv3d(256->512,3x3x3,SAME)+ReLU -> heads -> proposals
// Round-26 = r24 restored (final consolidated best).
// r25 post-mortem: 64o tile doubled B traffic (FETCH 239->710MB, L2 thrash
// across XCDs) -> conv 728us despite 2x occupancy. Confirms 128x128 tile at
// 2 blocks/CU is the L2-feasible optimum of this kernel family:
//  - conv: r16 pipelined structure (LDS dbuf + A-reg dbuf + B raw prefetch)
//    + LDS-only barriers. 565us, 58% MfmaUtil, bit-exact.
//  - fused heads3/heads2/prep, 4-stage NMS (propA/iou/nms).
// ---------------------------------------------------------------------------

#define T_DIM 16
#define H_DIM 32
#define W_DIM 32
#define NVOX  (T_DIM*H_DIM*W_DIM)   // 16384
#define HW    (H_DIM*W_DIM)         // 1024
#define CIN   256
#define COUT  512
#define PRE_NMS 1000
#define POST_NMS 128
#define NMS_TH 0.7f

typedef __attribute__((ext_vector_type(8))) short v8s;
typedef __attribute__((ext_vector_type(4))) float v4f;
typedef __attribute__((ext_vector_type(4))) int v4i;

#define MFMA_B16(A,B,C) __builtin_amdgcn_mfma_f32_16x16x32_bf16(A,B,C,0,0,0)

__device__ __forceinline__ short f2bf(float x) {
    unsigned u = __float_as_uint(x);
    u += 0x7FFFu + ((u >> 16) & 1u);
    return (short)(u >> 16);
}
__device__ __forceinline__ float bf2f(short s) {
    return __uint_as_float(((unsigned)(unsigned short)s) << 16);
}

__constant__ float c_ws[3] = {23.f, 16.f, 11.f};
__constant__ float c_hs[3] = {12.f, 16.f, 22.f};
__constant__ float c_sc[3] = {4.f, 8.f, 16.f};
__constant__ float c_depth[3] = {16.f, 8.f, 4.f};

// ---------------------------------------------------------------------------
// Weight split v2, FRAGMENT-MAJOR out: Af[((tap*32+ko)*512+o)*8+c7], c=ko*8+c7.
__global__ __launch_bounds__(256) void k_split_w(const float* __restrict__ W,
                                                 short* __restrict__ A0,
                                                 short* __restrict__ A1,
                                                 short* __restrict__ A2) {
    __shared__ float Wl[4][3456];         // 55.3 KB
    const int b = blockIdx.x;             // 256 blocks
    const int t = threadIdx.x;
    const int og = b >> 1;                // o = og*4 + ol
    const int ch = b & 1;                 // c = ch*128 + cl
#pragma unroll
    for (int k = 0; k < 54; ++k) {
        int fi = t + k * 256;             // 0..13823
        int ol = fi / 3456;
        int idx = fi - ol * 3456;         // = cl*27 + tap
        Wl[ol][idx] = W[(size_t)(og * 4 + ol) * 6912 + ch * 3456 + idx];
    }
    __syncthreads();
    for (int p = t; p < 432; p += 256) {
        int tap = p >> 4, kol = p & 15;
        int ko = ch * 16 + kol;
        v8s vh[4], vm[4], vl[4];
#pragma unroll
        for (int ol = 0; ol < 4; ++ol)
#pragma unroll
            for (int c7 = 0; c7 < 8; ++c7) {
                float x = Wl[ol][(kol * 8 + c7) * 27 + tap];
                short hh = f2bf(x); float r = x - bf2f(hh);
                short mm = f2bf(r); float r2 = r - bf2f(mm);
                short ll = f2bf(r2);
                vh[ol][c7] = hh; vm[ol][c7] = mm; vl[ol][c7] = ll;
            }
        size_t base = ((size_t)(tap * 32 + ko) * 512 + og * 4) * 8;
#pragma unroll
        for (int q = 0; q < 4; ++q) {
            *(v8s*)(A0 + base + q * 8) = vh[q];
            *(v8s*)(A1 + base + q * 8) = vm[q];
            *(v8s*)(A2 + base + q * 8) = vl[q];
        }
    }
}

// ---------------------------------------------------------------------------
// bit-trick split of 2 floats -> 3 packed bf16-pair ints (low = X0, high = X1)
// h = top16(x) [trunc]; r = x-h exact; m = top16(r); l = top16(r-m).
#define SPLIT2(X0, X1, OH, OM, OL) {                                          \
    unsigned u0_ = __float_as_uint(X0), u1_ = __float_as_uint(X1);            \
    OH = (int)__builtin_amdgcn_perm(u1_, u0_, 0x07060302u);                   \
    float h0_ = __uint_as_float(u0_ & 0xFFFF0000u);                           \
    float h1_ = __uint_as_float(u1_ & 0xFFFF0000u);                           \
    float r0_ = (X0) - h0_, r1_ = (X1) - h1_;                                 \
    unsigned v0_ = __float_as_uint(r0_), v1_ = __float_as_uint(r1_);          \
    OM = (int)__builtin_amdgcn_perm(v1_, v0_, 0x07060302u);                   \
    float m0_ = __uint_as_float(v0_ & 0xFFFF0000u);                           \
    float m1_ = __uint_as_float(v1_ & 0xFFFF0000u);                           \
    float s0_ = r0_ - m0_, s1_ = r1_ - m1_;                                   \
    OL = (int)__builtin_amdgcn_perm(__float_as_uint(s1_),                     \
                                    __float_as_uint(s0_), 0x07060302u);       \
}

// k_prep: fused  (a) Wcomb build [512 blocks]  (b) input pre-split [2048 blocks].
__global__ void k_prep(const float* __restrict__ Wcls, const float* __restrict__ Wbb,
                       float* __restrict__ Wc, const float* __restrict__ I,
                       v4i* __restrict__ Ih, v4i* __restrict__ Im,
                       v4i* __restrict__ Il) {
    int blk = blockIdx.x;
    if (blk < 512) {
        int i = blk * 256 + threadIdx.x;  // over 512*256
        int o = i & 255;
        int c = i >> 8;
        float v = 0.f;
        if (o < 54) v = Wcls[o * 512 + c];
        else if (o < 216) v = Wbb[(o - 54) * 512 + c];
        Wc[i] = v;
    } else {
        int t = (blk - 512) * 256 + threadIdx.x;   // over 32*16384 = 524288
        int vox = t & 16383;
        int ck8 = t >> 14;
        const float* ip = I + ((size_t)ck8 << 3) * NVOX + vox;
        int h[4], m[4], l[4];
#pragma unroll
        for (int j = 0; j < 4; ++j) {
            float x0 = ip[(size_t)(2 * j) * NVOX];
            float x1 = ip[(size_t)(2 * j + 1) * NVOX];
            SPLIT2(x0, x1, h[j], m[j], l[j]);
        }
        Ih[t] = (v4i){h[0], h[1], h[2], h[3]};
        Im[t] = (v4i){m[0], m[1], m[2], m[3]};
        Il[t] = (v4i){l[0], l[1], l[2], l[3]};
    }
}

#define CV_SHIFT(TAP) {                                                       \
    int kt_ = (TAP) / 9 - 1, kh_ = ((TAP) / 3) % 3 - 1, kw_ = (TAP) % 3 - 1;  \
    int tt_ = bt + kt_, hh_ = bh + kh_, ww_ = bw + kw_;                       \
    bVal = ((unsigned)tt_ < 16u) && ((unsigned)hh_ < 32u) && ((unsigned)ww_ < 32u); \
    bOff = bVal ? ((tt_ << 10) + (hh_ << 5) + ww_) : 0;                       \
}

// prefetch pre-split B raw regs (in flight during compute).
#define CV_LOAD_BP(CK8B) {                                                    \
    const size_t bidx_ = (((size_t)((CK8B) + skh * 2)) << 14) + bOff;         \
    nh0 = Ih[bidx_]; nh1 = Ih[bidx_ + NVOX];                                  \
    nm0 = Im[bidx_]; nm1 = Im[bidx_ + NVOX];                                  \
    nl0 = Il[bidx_]; nl1 = Il[bidx_ + NVOX];                                  \
}

#define LOAD_ASET_M(S, H0,H1,H2,H3, M0,M1,M2,M3, L0,L1,L2,L3) {               \
    const size_t aB_ = (((size_t)((S) >> 3) * 32 + (((S) & 7) << 2)) << 12) + aLane; \
    H0 = *(const v8s*)(A0 + aB_);       H1 = *(const v8s*)(A0 + aB_ + 128);   \
    H2 = *(const v8s*)(A0 + aB_ + 256); H3 = *(const v8s*)(A0 + aB_ + 384);   \
    M0 = *(const v8s*)(A1 + aB_);       M1 = *(const v8s*)(A1 + aB_ + 128);   \
    M2 = *(const v8s*)(A1 + aB_ + 256); M3 = *(const v8s*)(A1 + aB_ + 384);   \
    L0 = *(const v8s*)(A2 + aB_);       L1 = *(const v8s*)(A2 + aB_ + 128);   \
    L2 = *(const v8s*)(A2 + aB_ + 256); L3 = *(const v8s*)(A2 + aB_ + 384);   \
}

#define COMPUTE_M(BUF, H0,H1,H2,H3, M0,M1,M2,M3, L0,L1,L2,L3) {               \
    _Pragma("unroll")                                                         \
    for (int j = 0; j < 4; ++j) {                                             \
        v8s bb = *(const v8s*)(&Bsh[BUF][0][uB + j * 16]);                    \
        v8s bm = *(const v8s*)(&Bsh[BUF][1][uB + j * 16]);                    \
        v8s bl = *(const v8s*)(&Bsh[BUF][2][uB + j * 16]);                    \
        v4f a;                                                                \
        a = acc[0][j];                                                        \
        a = MFMA_B16(H0, bb, a); a = MFMA_B16(H0, bm, a);                     \
        a = MFMA_B16(M0, bb, a); a = MFMA_B16(H0, bl, a);                     \
        a = MFMA_B16(M0, bm, a); a = MFMA_B16(L0, bb, a);                     \
        acc[0][j] = a;                                                        \
        a = acc[1][j];                                                        \
        a = MFMA_B16(H1, bb, a); a = MFMA_B16(H1, bm, a);                     \
        a = MFMA_B16(M1, bb, a); a = MFMA_B16(H1, bl, a);                     \
        a = MFMA_B16(M1, bm, a); a = MFMA_B16(L1, bb, a);                     \
        acc[1][j] = a;                                                        \
        a = acc[2][j];                                                        \
        a = MFMA_B16(H2, bb, a); a = MFMA_B16(H2, bm, a);                     \
        a = MFMA_B16(M2, bb, a); a = MFMA_B16(H2, bl, a);                     \
        a = MFMA_B16(M2, bm, a); a = MFMA_B16(L2, bb, a);                     \
        acc[2][j] = a;                                                        \
        a = acc[3][j];                                                        \
        a = MFMA_B16(H3, bb, a); a = MFMA_B16(H3, bm, a);                     \
        a = MFMA_B16(M3, bb, a); a = MFMA_B16(H3, bl, a);                     \
        a = MFMA_B16(M3, bm, a); a = MFMA_B16(L3, bb, a);                     \
        acc[3][j] = a;                                                        \
    }                                                                         \
}

// Variadic forwarders: expand ASET(x) before parameter matching.
#define LOAD_ASET(S, ...) LOAD_ASET_M(S, __VA_ARGS__)
#define COMPUTE(BUF, ...) COMPUTE_M(BUF, __VA_ARGS__)

#define ASET(P) P##h0,P##h1,P##h2,P##h3,P##m0,P##m1,P##m2,P##m3,P##l0,P##l1,P##l2,P##l3

#define ITER_BODY(SS, BUF, CUR, ALT) {                                        \
    int s1_ = (SS) + 1, s2_ = (SS) + 2;                                       \
    if (s1_ < 216) { LOAD_ASET(s1_, ASET(ALT)); }                             \
    if (s1_ < 216) {                                                          \
        v4i z_ = (v4i){0, 0, 0, 0};                                           \
        Bsh[(BUF) ^ 1][0][uW0] = bValCur ? nh0 : z_;                          \
        Bsh[(BUF) ^ 1][0][uW1] = bValCur ? nh1 : z_;                          \
        Bsh[(BUF) ^ 1][1][uW0] = bValCur ? nm0 : z_;                          \
        Bsh[(BUF) ^ 1][1][uW1] = bValCur ? nm1 : z_;                          \
        Bsh[(BUF) ^ 1][2][uW0] = bValCur ? nl0 : z_;                          \
        Bsh[(BUF) ^ 1][2][uW1] = bValCur ? nl1 : z_;                          \
    }                                                                         \
    if (s2_ < 216) {                                                          \
        if ((s2_ & 7) == 0) CV_SHIFT(s2_ >> 3);                               \
        CV_LOAD_BP((s2_ & 7) << 2);                                           \
        bValCur = bVal;                                                       \
    }                                                                         \
    COMPUTE(BUF, ASET(CUR));                                                  \
}

// LDS-only barrier: order LDS ops (lgkmcnt) but let global prefetches stay
// in flight across the barrier (counted-wait pattern).
#define BAR_LDS() { asm volatile("s_waitcnt lgkmcnt(0)" ::: "memory");        \
                    __builtin_amdgcn_s_barrier(); }

// MFMA conv3d: 128x128 block tile, 4 waves in 2x2 (each 64o x 64v), BK=32.
// Fully pipelined: LDS dbuf (1 barrier/iter) + A-reg dbuf + B raw prefetch.
__global__ __launch_bounds__(256, 2) void k_conv3d_mfma(
        const v4i* __restrict__ Ih, const v4i* __restrict__ Im,
        const v4i* __restrict__ Il, const short* __restrict__ A0,
        const short* __restrict__ A1, const short* __restrict__ A2,
        const float* __restrict__ bias, float* __restrict__ O) {
    __shared__ v4i Bsh[2][3][512];   // 48 KB (double-buffered)
    const int tid = threadIdx.x;
    const int o0 = blockIdx.y * 128;
    const int v0 = blockIdx.x * 128;
    const int lane = tid & 63;
    const int wv = tid >> 6;
    const int quad = lane >> 4, m16 = lane & 15;
    const int wo = (wv >> 1) * 64;        // wave o-origin within tile
    const int wvx = (wv & 1) * 64;        // wave v-origin within tile

    // B staging: row sa_o = tid>>1 (0..127), k-half skh = tid&1
    const int sa_o = tid >> 1, skh = tid & 1;
    const int uW0 = (skh * 2) * 128 + sa_o;
    const int uW1 = (skh * 2 + 1) * 128 + sa_o;

    const int vbase = v0 + sa_o;
    const int bt = vbase >> 10, bh = (vbase >> 5) & 31, bw = vbase & 31;

    // B fragment read base: [quad*128 + wvx + j*16 + m16]
    const int uB = quad * 128 + wvx + m16;

    // A fragment global base offset (shorts): lane part
    const size_t aLane = ((size_t)(o0 + wo + m16) << 3) + ((size_t)quad << 12);

    v4f acc[4][4];
#pragma unroll
    for (int i = 0; i < 4; i++)
#pragma unroll
        for (int j = 0; j < 4; j++) acc[i][j] = (v4f){0.f, 0.f, 0.f, 0.f};

    int bOff, bVal, bValCur;
    v4i nh0, nh1, nm0, nm1, nl0, nl1;
    v8s Ph0, Ph1, Ph2, Ph3, Pm0, Pm1, Pm2, Pm3, Pl0, Pl1, Pl2, Pl3;
    v8s Qh0, Qh1, Qh2, Qh3, Qm0, Qm1, Qm2, Qm3, Ql0, Ql1, Ql2, Ql3;

    // prologue: stage-0 B into buf0, raw(1) in flight, A(0) in P
    CV_SHIFT(0);
    bValCur = bVal;
    CV_LOAD_BP(0);
    {
        v4i z_ = (v4i){0, 0, 0, 0};
        Bsh[0][0][uW0] = bValCur ? nh0 : z_;
        Bsh[0][0][uW1] = bValCur ? nh1 : z_;
        Bsh[0][1][uW0] = bValCur ? nm0 : z_;
        Bsh[0][1][uW1] = bValCur ? nm1 : z_;
        Bsh[0][2][uW0] = bValCur ? nl0 : z_;
        Bsh[0][2][uW1] = bValCur ? nl1 : z_;
    }
    CV_LOAD_BP(4);                        // raw(1), tap 0 (bValCur unchanged)
    LOAD_ASET(0, ASET(P));
    __syncthreads();

    for (int s = 0; s < 216; s += 2) {
        ITER_BODY(s, 0, P, Q);            // compute buf0 with A(s)=P
        BAR_LDS();
        ITER_BODY(s + 1, 1, Q, P);        // compute buf1 with A(s+1)=Q
        BAR_LDS();
    }

    // epilogue: per 16x16 tile, col = m16 (v), row = quad*4 + reg (o)
#pragma unroll
    for (int i = 0; i < 4; ++i) {
#pragma unroll
        for (int r = 0; r < 4; ++r) {
            int o = o0 + wo + i * 16 + quad * 4 + r;
            float bo = bias[o];
            float* dst = O + (size_t)o * NVOX + v0 + wvx + m16;
#pragma unroll
            for (int j = 0; j < 4; ++j)
                dst[j * 16] = fmaxf(acc[i][j][r] + bo, 0.f);
        }
    }
}

// ---------------------------------------------------------------------------
// logits3 GEMM: L[o][v] = sum_c Wc[c][o] * conv1[c][v], M=256 (padded), K=512, N=16384
__global__ __launch_bounds__(256) void k_gemm_logits3(const float* __restrict__ conv1,
                                                      const float* __restrict__ Wc,
                                                      float* __restrict__ L) {
    __shared__ float As[16][64];
    __shared__ float Bs[16][64];
    const int tid = threadIdx.x;
    const int o0 = blockIdx.y * 64;
    const int v0 = blockIdx.x * 64;
    const int ty = tid >> 4, tx = tid & 15;
    const int c_l = tid >> 4, e4 = (tid & 15) << 2;

    float acc[4][4];
#pragma unroll
    for (int i = 0; i < 4; i++)
#pragma unroll
        for (int j = 0; j < 4; j++) acc[i][j] = 0.f;

    for (int ck = 0; ck < 512; ck += 16) {
        __syncthreads();
        *(float4*)(&As[c_l][e4]) = *(const float4*)(Wc + ((size_t)(ck + c_l) << 8) + o0 + e4);
        *(float4*)(&Bs[c_l][e4]) = *(const float4*)(conv1 + ((size_t)(ck + c_l) << 14) + v0 + e4);
        __syncthreads();
#pragma unroll
        for (int k = 0; k < 16; ++k) {
            float a[4], b[4];
            *(float4*)(a) = *(const float4*)(&As[k][ty * 4]);
            *(float4*)(b) = *(const float4*)(&Bs[k][tx * 4]);
#pragma unroll
            for (int i = 0; i < 4; i++)
#pragma unroll
                for (int j = 0; j < 4; j++)
                    acc[i][j] = fmaf(a[i], b[j], acc[i][j]);
        }
    }
#pragma unroll
    for (int i = 0; i < 4; i++) {
        float* dst = L + (size_t)(o0 + ty * 4 + i) * NVOX + v0 + tx * 4;
        *(float4*)(dst) = *(const float4*)(&acc[i][0]);
    }
}

// ---------------------------------------------------------------------------
// Fused heads for the 3D branch: sc3 | dl3 | feat2 in one launch.
__global__ void k_heads3(const float* __restrict__ L, const float* __restrict__ b_cls,
                         const float* __restrict__ b_bbox, const float* __restrict__ conv1,
                         float* __restrict__ sc3, float* __restrict__ dl3,
                         float* __restrict__ feat2) {
    int i = blockIdx.x * 256 + threadIdx.x;
    if (i < 27 * HW) {
        int a = i >> 10, hw = i & 1023;
        float b0 = b_cls[a], b1 = b_cls[27 + a];
        const float* L0 = L + (size_t)a * NVOX + hw;
        const float* L1 = L + (size_t)(27 + a) * NVOX + hw;
        float s = 0.f;
        for (int t = 0; t < T_DIM; t++) {
            float x0 = L0[t * HW] + b0, x1 = L1[t * HW] + b1;
            float m = fmaxf(x0, x1);
            float e0 = expf(x0 - m), e1 = expf(x1 - m);
            s += e1 / (e0 + e1);
        }
        sc3[hw * 27 + a] = s * (1.f / 16.f);
    } else if (i < (27 + 162) * HW) {
        int ii = i - 27 * HW;
        int ch = ii >> 10, hw = ii & 1023;
        const float* Lr = L + (size_t)(54 + ch) * NVOX + hw;
        float s = 0.f;
        for (int t = 0; t < T_DIM; t++) s += Lr[t * HW];
        s = s * (1.f / 16.f) + b_bbox[ch];
        int a = ch / 6, d = ch - a * 6;
        dl3[((size_t)hw * 27 + a) * 6 + d] = s;
    } else {
        int ii = i - (27 + 162) * HW;   // 0..524287
        int c = ii >> 10, hw = ii & 1023;
        const float* src = conv1 + (size_t)c * NVOX + hw;
        float s = 0.f;
        for (int t = 0; t < T_DIM; t++) s += src[t * HW];
        feat2[ii] = s * (1.f / 16.f);
    }
}

__global__ void k_gemm2d(const float* __restrict__ feat2, const float* __restrict__ Wcls16,
                         const float* __restrict__ Wbb16, float* __restrict__ L2) {
    int g = blockIdx.x * 256 + threadIdx.x;   // 55296
    int o = g >> 10, hw = g & 1023;
    const float* wrow = (o < 18) ? (Wcls16 + (size_t)o * 512) : (Wbb16 + (size_t)(o - 18) * 512);
    float s = 0.f;
    for (int c = 0; c < 512; c++) s = fmaf(wrow[c], feat2[(size_t)c * HW + hw], s);
    L2[(size_t)o * HW + hw] = s;
}

// Fused heads for the 2D branch: sc2 | dl2 (9*HW + 36*HW = 180 blocks).
__global__ void k_heads2(const float* __restrict__ L2, const float* __restrict__ b_cls16,
                         const float* __restrict__ b_bbox16,
                         float* __restrict__ sc2, float* __restrict__ dl2) {
    int i = blockIdx.x * 256 + threadIdx.x;
    if (i < 9 * HW) {
        int a = i >> 10, hw = i & 1023;
        float x0 = L2[(size_t)a * HW + hw] + b_cls16[a];
        float x1 = L2[(size_t)(9 + a) * HW + hw] + b_cls16[9 + a];
        float m = fmaxf(x0, x1);
        float e0 = expf(x0 - m), e1 = expf(x1 - m);
        sc2[hw * 9 + a] = e1 / (e0 + e1);
    } else if (i < 45 * HW) {
        int ii = i - 9 * HW;
        int ch = ii >> 10, hw = ii & 1023;
        float v = L2[(size_t)(18 + ch) * HW + hw] + b_bbox16[ch];
        int a = ch >> 2, d = ch & 3;
        dl2[((size_t)hw * 9 + a) * 4 + d] = v;
    }
}

// ---------------------------------------------------------------------------
__device__ __forceinline__ unsigned mapf(float f) {
    unsigned u = __float_as_uint(f);
    return (u & 0x80000000u) ? ~u : (u | 0x80000000u);
}

// propA: radix-select + compaction + bitonic sort + decode -> bxg (global).
__global__ __launch_bounds__(1024) void k_propA(const float* __restrict__ im_info,
                                                const float* __restrict__ sc3,
                                                const float* __restrict__ dl3,
                                                const float* __restrict__ sc2,
                                                const float* __restrict__ dl2,
                                                float* __restrict__ bxg) {
    const int branch = blockIdx.x;
    const int tid = threadIdx.x;
    const int A = (branch == 0) ? 27 : 9;
    const int nd = (branch == 0) ? 3 : 2;
    const float* scores = (branch == 0) ? sc3 : sc2;
    const float* deltas = (branch == 0) ? dl3 : dl2;
    const int K = PRE_NMS;
    const int ept = A;
    const int base = tid * ept;

    __shared__ unsigned hist[256];
    __shared__ unsigned long long keys[1024];
    __shared__ unsigned wsum[16];
    __shared__ int sh_b, sh_next;

    // ================= radix-select =========================================
    unsigned prefix = 0;
    int rank = K;
    for (int shift = 24; shift >= 0; shift -= 8) {
        if (tid < 256) hist[tid] = 0;
        __syncthreads();
        const unsigned mask_hi = (shift == 24) ? 0u : (0xFFFFFFFFu << (shift + 8));
        for (int j = 0; j < ept; j++) {
            unsigned m = mapf(scores[base + j]);
            if ((m & mask_hi) == prefix)
                atomicAdd(&hist[(m >> shift) & 255], 1u);
        }
        __syncthreads();
        for (int d = 1; d < 256; d <<= 1) {
            unsigned add = 0;
            if (tid < 256 && tid + d < 256) add = hist[tid + d];
            __syncthreads();
            if (tid < 256) hist[tid] += add;
            __syncthreads();
        }
        if (tid < 256) {
            bool win = (hist[tid] >= (unsigned)rank) &&
                       (tid == 255 || hist[tid + 1] < (unsigned)rank);
            if (win) { sh_b = tid; sh_next = (tid == 255) ? 0 : (int)hist[tid + 1]; }
        }
        __syncthreads();
        prefix |= (unsigned)sh_b << shift;
        rank -= sh_next;
        __syncthreads();
    }
    const unsigned tau = prefix;

    // ================= compaction ===========================================
    int gt_c = 0, eq_c = 0;
    for (int j = 0; j < ept; j++) {
        unsigned m = mapf(scores[base + j]);
        gt_c += (m > tau);
        eq_c += (m == tau);
    }
    unsigned cnt = ((unsigned)gt_c << 16) | (unsigned)eq_c;
    const int lane = tid & 63, wid = tid >> 6;
    unsigned x = cnt;
    for (int d = 1; d < 64; d <<= 1) {
        unsigned y = __shfl_up(x, d);
        if (lane >= d) x += y;
    }
    if (lane == 63) wsum[wid] = x;
    __syncthreads();
    if (wid == 0) {
        unsigned w = (lane < 16) ? wsum[lane] : 0;
        for (int d = 1; d < 16; d <<= 1) {
            unsigned y = __shfl_up(w, d);
            if (lane >= d) w += y;
        }
        if (lane < 16) wsum[lane] = w;
    }
    __syncthreads();
    unsigned excl = x - cnt + (wid ? wsum[wid - 1] : 0);
    const int c1 = (int)(wsum[15] >> 16);
    int gi = (int)(excl >> 16);
    int ei = (int)(excl & 0xFFFFu);
    for (int j = 0; j < ept; j++) {
        int idx = base + j;
        unsigned m = mapf(scores[idx]);
        unsigned long long key = ((unsigned long long)m << 32) |
                                 (unsigned)(0xFFFFFFFFu - (unsigned)idx);
        if (m > tau) {
            keys[gi++] = key;
        } else if (m == tau) {
            if (c1 + ei < K) keys[c1 + ei] = key;
            ei++;
        }
    }
    if (tid < 1024 - K) keys[K + tid] = 0;
    __syncthreads();

    // ================= bitonic sort (desc) ==================================
    for (int k = 2; k <= 1024; k <<= 1) {
        for (int j = k >> 1; j > 0; j >>= 1) {
            int ixj = tid ^ j;
            if (ixj > tid) {
                unsigned long long a = keys[tid], b = keys[ixj];
                bool sw2 = ((tid & k) == 0) ? (a < b) : (a > b);
                if (sw2) { keys[tid] = b; keys[ixj] = a; }
            }
            __syncthreads();
        }
    }

    // ================= decode + clip -> bxg =================================
    const float imh = im_info[0], imw = im_info[1];
    if (tid < K) {
        int n = (int)(0xFFFFFFFFu - (unsigned)(keys[tid] & 0xFFFFFFFFull));
        int cell = n / A, a = n - cell * A;
        int hc = cell >> 5, wc = cell & 31;
        int a2 = (branch == 0) ? (a % 9) : a;
        int ri = a2 / 3, si = a2 % 3;
        float w = c_ws[ri] * c_sc[si], h = c_hs[ri] * c_sc[si];
        float lo[3], hi[3], mx[3];
        lo[0] = 7.5f - (w - 1.f) * 0.5f + 16.f * wc;
        hi[0] = 7.5f + (w - 1.f) * 0.5f + 16.f * wc;
        mx[0] = imw - 1.f;
        lo[1] = 7.5f - (h - 1.f) * 0.5f + 16.f * hc;
        hi[1] = 7.5f + (h - 1.f) * 0.5f + 16.f * hc;
        mx[1] = imh - 1.f;
        if (branch == 0) { lo[2] = 0.f; hi[2] = c_depth[a / 9] - 1.f; mx[2] = (float)(T_DIM - 1); }
        const float* dp = deltas + (size_t)n * (2 * nd);
        float* bp = bxg + ((size_t)branch * PRE_NMS + tid) * 6;
        for (int d = 0; d < nd; d++) {
            float size = hi[d] - lo[d] + 1.f;
            float ctr = lo[d] + 0.5f * (size - 1.f);
            float pctr = dp[d] * size + ctr;
            float psize = expf(dp[nd + d]) * size;
            float pl = pctr - 0.5f * (psize - 1.f);
            float ph = pctr + 0.5f * (psize - 1.f);
            bp[d]      = fminf(fmaxf(pl, 0.f), mx[d]);
            bp[nd + d] = fminf(fmaxf(ph, 0.f), mx[d]);
        }
    }
}

// k_iou: suppression bitmask matrix. Same FP formula/order as the original
// in-loop IoU -> identical comparison bits -> identical keep list.
__global__ __launch_bounds__(256) void k_iou(const float* __restrict__ bxg,
                                             unsigned long long* __restrict__ masks) {
    int g = blockIdx.x * 256 + threadIdx.x;   // 2*1000*16 = 32000
    if (g >= 2 * PRE_NMS * 16) return;
    int branch = g / (PRE_NMS * 16);
    int rem = g - branch * (PRE_NMS * 16);
    int r = rem >> 4, w = rem & 15;
    int nd = (branch == 0) ? 3 : 2;
    const float* B = bxg + (size_t)branch * PRE_NMS * 6;
    float rb[6];
#pragma unroll
    for (int d = 0; d < 6; d++) rb[d] = B[(size_t)r * 6 + d];
    unsigned long long mword = 0;
    int c0 = w * 64;
    for (int j = 0; j < 64; ++j) {
        int c = c0 + j;
        if (c >= PRE_NMS) break;
        const float* cb = B + (size_t)c * 6;
        float colvol = 1.f;
        for (int d = 0; d < nd; d++) colvol *= (cb[nd + d] - cb[d] + 1.f);
        float inter = 1.f, rvol = 1.f;
        for (int d = 0; d < nd; d++) {
            float slo = rb[d], shi = rb[nd + d];
            float l = fmaxf(slo, cb[d]);
            float hh = fminf(shi, cb[nd + d]);
            inter *= fmaxf(hh - l + 1.f, 0.f);
            rvol *= (shi - slo + 1.f);
        }
        float iou = inter / (rvol + colvol - inter);
        if ((iou > NMS_TH) || (c == r)) mword |= (1ull << j);
    }
    masks[((size_t)branch * PRE_NMS + r) * 16 + w] = mword;
}

// k_nms: greedy over bitmask rows (one wave per branch, alive in registers)
// + fused output write (keep list via LDS, same block).
__global__ __launch_bounds__(64) void k_nms(const unsigned long long* __restrict__ masks,
                                            const float* __restrict__ bxg,
                                            float* __restrict__ out) {
    const int branch = blockIdx.x;
    const int lane = threadIdx.x;
    const unsigned long long* M = masks + (size_t)branch * PRE_NMS * 16;
    __shared__ int keep[POST_NMS];
    unsigned long long alive = 0;
    if (lane < 15) alive = ~0ull;
    else if (lane == 15) alive = (1ull << (PRE_NMS - 15 * 64)) - 1;
    for (int i = 0; i < POST_NMS; ++i) {
        int cand = (lane < 16 && alive) ? (lane * 64 + __ffsll(alive) - 1) : 0x7fffffff;
#pragma unroll
        for (int off = 32; off; off >>= 1)
            cand = min(cand, __shfl_xor(cand, off));
        int sel = (cand == 0x7fffffff) ? 0 : cand;
        if (lane == 0) keep[i] = sel;
        if (lane < 16) alive &= ~M[(size_t)sel * 16 + lane];
    }
    __syncthreads();
    const float* B = bxg + (size_t)branch * PRE_NMS * 6;
    for (int e = lane; e < POST_NMS; e += 64) {
        int k = keep[e];
        if (branch == 0) {
            float* o = out + (size_t)e * 7;
            o[0] = 0.f;
            for (int d = 0; d < 6; d++) o[1 + d] = B[(size_t)k * 6 + d];
        } else {
            float* o = out + 128 * 7 + (size_t)e * 5;
            o[0] = 0.f;
            for (int d = 0; d < 4; d++) o[1 + d] = B[(size_t)k * 6 + d];
        }
    }
    if (branch == 0 && lane == 0) {
        out[1536] = 0.f; out[1537] = 0.f; out[1538] = 0.f; out[1539] = 0.f;
    }
}

// ---------------------------------------------------------------------------
extern "C" void kernel_launch(void* const* d_in, const int* in_sizes, int n_in,
                              void* d_out, int out_size, void* d_ws, size_t ws_size,
                              hipStream_t stream) {
    (void)in_sizes; (void)n_in; (void)out_size; (void)ws_size;
    const float* base_feat = (const float*)d_in[0];
    const float* im_info   = (const float*)d_in[1];
    const float* W_conv    = (const float*)d_in[4];
    const float* b_conv    = (const float*)d_in[5];
    const float* W_cls     = (const float*)d_in[6];
    const float* b_cls     = (const float*)d_in[7];
    const float* W_bbox    = (const float*)d_in[8];
    const float* b_bbox    = (const float*)d_in[9];
    const float* W_cls16   = (const float*)d_in[10];
    const float* b_cls16   = (const float*)d_in[11];
    const float* W_bbox16  = (const float*)d_in[12];
    const float* b_bbox16  = (const float*)d_in[13];
    float* out = (float*)d_out;

    // workspace: A0/A1/A2 (bf16 splits, dead after conv) alias L3
    char* ws = (char*)d_ws;
    const size_t AW = (size_t)27 * 512 * 256;
    short* A0 = (short*)ws;
    short* A1 = A0 + AW;
    short* A2 = A1 + AW;
    float* L3 = (float*)ws;
    size_t off = AW * 3 * sizeof(short);
    float* Wcomb  = (float*)(ws + off); off += (size_t)512 * 256 * 4;
    float* conv1  = (float*)(ws + off); off += (size_t)COUT * NVOX * 4;
    float* feat2  = (float*)(ws + off); off += (size_t)512 * HW * 4;
    float* L2     = (float*)(ws + off); off += (size_t)64 * HW * 4;
    float* sc3    = (float*)(ws + off); off += (size_t)27 * HW * 4;
    float* dl3    = (float*)(ws + off); off += (size_t)27 * HW * 6 * 4;
    float* sc2    = (float*)(ws + off); off += (size_t)9 * HW * 4;
    float* dl2    = (float*)(ws + off); off += (size_t)9 * HW * 4 * 4;
    // pre-split input planes (v4i = 8 channels bf16-pair packed), 8.4 MB each
    v4i* Ih = (v4i*)(ws + off); off += (size_t)32 * NVOX * 16;
    v4i* Im_ = (v4i*)(ws + off); off += (size_t)32 * NVOX * 16;
    v4i* Il = (v4i*)(ws + off); off += (size_t)32 * NVOX * 16;
    // proposal pipeline scratch
    float* bxg = (float*)(ws + off); off += (size_t)2 * PRE_NMS * 6 * 4;
    unsigned long long* masks = (unsigned long long*)(ws + off);
    off += (size_t)2 * PRE_NMS * 16 * 8;

    k_split_w<<<256, 256, 0, stream>>>(W_conv, A0, A1, A2);
    k_prep<<<512 + 2048, 256, 0, stream>>>(W_cls, W_bbox, Wcomb, base_feat, Ih, Im_, Il);
    {
        dim3 g(NVOX / 128, COUT / 128);
        k_conv3d_mfma<<<g, 256, 0, stream>>>(Ih, Im_, Il, A0, A1, A2, b_conv, conv1);
    }
    {
        dim3 g(NVOX / 64, 4);
        k_gemm_logits3<<<g, 256, 0, stream>>>(conv1, Wcomb, L3);
    }
    k_heads3<<<(27 + 162 + 512) * HW / 256, 256, 0, stream>>>(L3, b_cls, b_bbox, conv1,
                                                              sc3, dl3, feat2);
    k_gemm2d<<<(54 * HW) / 256, 256, 0, stream>>>(feat2, W_cls16, W_bbox16, L2);
    k_heads2<<<(45 * HW) / 256, 256, 0, stream>>>(L2, b_cls16, b_bbox16, sc2, dl2);
    k_propA<<<2, 1024, 0, stream>>>(im_info, sc3, dl3, sc2, dl2, bxg);
    k_iou<<<(2 * PRE_NMS * 16 + 255) / 256, 256, 0, stream>>>(bxg, masks);
    k_nms<<<2, 64, 0, stream>>>(masks, bxg, out);
}